// Round 1
// baseline (1628.956 us; speedup 1.0000x reference)
//
#include <hip/hip_runtime.h>

// GCN 2-layer:
//   h1 = x @ W1                          [N,128]@[128,64]
//   agg1 = segment_sum(h1[src]*w, dst)   + b1, relu
//   h2 = relu(agg1+b1) @ W2              [N,64]@[64,32]
//   out = segment_sum(h2[src]*w, dst) + b2

#define F4C(v, j) ((j)==0?(v).x:((j)==1?(v).y:((j)==2?(v).z:(v).w)))

// ---------------- GEMM1: h1 = x @ W1 ----------------
// Block: 256 threads -> 64-row x 64-col tile, each thread 4x4 outputs.
// xs padded to 132 (row bank-shift 4 -> worst 2-way conflict, free).
__global__ __launch_bounds__(256, 2) void gemm1_kernel(
    const float* __restrict__ x, const float* __restrict__ W1,
    float* __restrict__ h1, int N)
{
    __shared__ __align__(16) float xs[64][132];
    __shared__ __align__(16) float ws[128][64];
    const int tid  = threadIdx.x;
    const int row0 = blockIdx.x * 64;

    // stage W1 (128x64 = 2048 float4)
    {
        const float4* W4 = (const float4*)W1;
        float4* d4 = (float4*)&ws[0][0];
        #pragma unroll
        for (int i = 0; i < 8; i++) d4[tid + i*256] = W4[tid + i*256];
    }
    // stage x tile (64 rows x 128 = 2048 float4)
    {
        const float4* x4 = (const float4*)x;
        #pragma unroll
        for (int i = 0; i < 8; i++) {
            int idx = tid + i*256;
            int r = idx >> 5, kc = idx & 31;
            int gr = row0 + r;
            float4 v = make_float4(0.f,0.f,0.f,0.f);
            if (gr < N) v = x4[gr*32 + kc];
            *(float4*)&xs[r][kc*4] = v;
        }
    }
    __syncthreads();

    const int c0 = (tid & 15) * 4;   // 16 col-groups x 4 cols
    const int r0 = (tid >> 4) * 4;   // 16 row-groups x 4 rows
    float acc[4][4] = {};
    for (int k = 0; k < 128; k += 4) {
        float4 xv[4], wv[4];
        #pragma unroll
        for (int i = 0; i < 4; i++) xv[i] = *(const float4*)&xs[r0 + i][k];
        #pragma unroll
        for (int kk = 0; kk < 4; kk++) wv[kk] = *(const float4*)&ws[k + kk][c0];
        #pragma unroll
        for (int i = 0; i < 4; i++) {
            #pragma unroll
            for (int j = 0; j < 4; j++) {
                acc[i][j] += F4C(xv[i],0) * F4C(wv[0],j)
                           + F4C(xv[i],1) * F4C(wv[1],j)
                           + F4C(xv[i],2) * F4C(wv[2],j)
                           + F4C(xv[i],3) * F4C(wv[3],j);
            }
        }
    }
    #pragma unroll
    for (int i = 0; i < 4; i++) {
        int gr = row0 + r0 + i;
        if (gr < N)
            *(float4*)&h1[gr*64 + c0] =
                make_float4(acc[i][0], acc[i][1], acc[i][2], acc[i][3]);
    }
}

// ---------------- Scatter1: agg1[dst] += h1[src]*w (64 feats/edge) --------
__global__ __launch_bounds__(256) void scatter1_kernel(
    const float* __restrict__ h1, const int* __restrict__ src,
    const int* __restrict__ dst, const float* __restrict__ w,
    float* __restrict__ agg, int E)
{
    int gid = blockIdx.x * 256 + threadIdx.x;   // E*64 = 102.4M < 2^31
    int e = gid >> 6;
    if (e >= E) return;
    int lane = gid & 63;
    int s = src[e], d = dst[e];
    float v = h1[s*64 + lane] * w[e];
    unsafeAtomicAdd(&agg[d*64 + lane], v);
}

// ---------------- Layer2 fused: h2 = relu(agg1+b1) @ W2 ----------------
// Block: 64-node x 32-col tile; thread = 2 nodes x 4 cols.
__global__ __launch_bounds__(256, 2) void layer2_kernel(
    const float* __restrict__ agg1, const float* __restrict__ b1,
    const float* __restrict__ W2, float* __restrict__ h2, int N)
{
    __shared__ __align__(16) float ts[64][68];
    __shared__ __align__(16) float w2s[64][32];
    const int tid   = threadIdx.x;
    const int node0 = blockIdx.x * 64;

    // stage W2 (64x32 = 512 float4)
    {
        const float4* s4 = (const float4*)W2;
        float4* d4 = (float4*)&w2s[0][0];
        #pragma unroll
        for (int i = 0; i < 2; i++) d4[tid + i*256] = s4[tid + i*256];
    }
    // stage t = relu(agg1 + b1) (64 nodes x 64 = 1024 float4)
    {
        const float4* a4 = (const float4*)agg1;
        const float4* b4 = (const float4*)b1;
        #pragma unroll
        for (int i = 0; i < 4; i++) {
            int idx = tid + i*256;
            int r = idx >> 4, kc = idx & 15;
            int gn = node0 + r;
            float4 v = make_float4(0.f,0.f,0.f,0.f);
            if (gn < N) {
                v = a4[gn*16 + kc];
                float4 bb = b4[kc];
                v.x = fmaxf(v.x + bb.x, 0.f);
                v.y = fmaxf(v.y + bb.y, 0.f);
                v.z = fmaxf(v.z + bb.z, 0.f);
                v.w = fmaxf(v.w + bb.w, 0.f);
            }
            *(float4*)&ts[r][kc*4] = v;
        }
    }
    __syncthreads();

    const int c0 = (tid & 7) * 4;    // 8 col-groups x 4 cols
    const int n0 = (tid >> 3) * 2;   // 32 node-groups x 2 nodes
    float acc[2][4] = {};
    for (int k = 0; k < 64; k += 4) {
        float4 tv[2], wv[4];
        tv[0] = *(const float4*)&ts[n0][k];
        tv[1] = *(const float4*)&ts[n0 + 1][k];
        #pragma unroll
        for (int kk = 0; kk < 4; kk++) wv[kk] = *(const float4*)&w2s[k + kk][c0];
        #pragma unroll
        for (int i = 0; i < 2; i++) {
            #pragma unroll
            for (int j = 0; j < 4; j++) {
                acc[i][j] += F4C(tv[i],0) * F4C(wv[0],j)
                           + F4C(tv[i],1) * F4C(wv[1],j)
                           + F4C(tv[i],2) * F4C(wv[2],j)
                           + F4C(tv[i],3) * F4C(wv[3],j);
            }
        }
    }
    #pragma unroll
    for (int i = 0; i < 2; i++) {
        int gn = node0 + n0 + i;
        if (gn < N)
            *(float4*)&h2[gn*32 + c0] =
                make_float4(acc[i][0], acc[i][1], acc[i][2], acc[i][3]);
    }
}

// ---------------- init out = b2 broadcast ----------------
__global__ __launch_bounds__(256) void init_out_kernel(
    const float* __restrict__ b2, float* __restrict__ out, int total)
{
    int i = blockIdx.x * 256 + threadIdx.x;
    if (i < total) out[i] = b2[i & 31];
}

// ---------------- Scatter2: out[dst] += h2[src]*w (32 feats/edge) --------
__global__ __launch_bounds__(256) void scatter2_kernel(
    const float* __restrict__ h2, const int* __restrict__ src,
    const int* __restrict__ dst, const float* __restrict__ w,
    float* __restrict__ out, int E)
{
    int gid = blockIdx.x * 256 + threadIdx.x;   // E*32 = 51.2M
    int e = gid >> 5;
    if (e >= E) return;
    int lane = gid & 31;
    int s = src[e], d = dst[e];
    float v = h2[s*32 + lane] * w[e];
    unsafeAtomicAdd(&out[d*32 + lane], v);
}

extern "C" void kernel_launch(void* const* d_in, const int* in_sizes, int n_in,
                              void* d_out, int out_size, void* d_ws, size_t ws_size,
                              hipStream_t stream)
{
    const float* x   = (const float*)d_in[0];
    const int*  esrc = (const int*)d_in[1];
    const int*  edst = (const int*)d_in[2];
    const float* ew  = (const float*)d_in[3];
    const float* W1  = (const float*)d_in[4];
    const float* b1  = (const float*)d_in[5];
    const float* W2  = (const float*)d_in[6];
    const float* b2  = (const float*)d_in[7];
    float* out = (float*)d_out;

    const int N = in_sizes[0] / 128;   // 100000
    const int E = in_sizes[1];         // 1600000

    // workspace: h1 [N*64], agg1 [N*64]; h2 reuses h1's region (N*32)
    float* h1   = (float*)d_ws;
    float* agg1 = h1 + (size_t)N * 64;
    float* h2   = h1;

    hipMemsetAsync(agg1, 0, (size_t)N * 64 * sizeof(float), stream);

    int tile_blocks = (N + 63) / 64;
    gemm1_kernel<<<tile_blocks, 256, 0, stream>>>(x, W1, h1, N);
    scatter1_kernel<<<(E * 64 + 255) / 256, 256, 0, stream>>>(h1, esrc, edst, ew, agg1, E);
    layer2_kernel<<<tile_blocks, 256, 0, stream>>>(agg1, b1, W2, h2, N);
    init_out_kernel<<<(N * 32 + 255) / 256, 256, 0, stream>>>(b2, out, N * 32);
    scatter2_kernel<<<(E * 32 + 255) / 256, 256, 0, stream>>>(h2, esrc, edst, ew, out, E);
}

// Round 2
// 1458.476 us; speedup vs baseline: 1.1169x; 1.1169x over previous
//
#include <hip/hip_runtime.h>
#include <hip/hip_bf16.h>

// GCN 2-layer, CSR-gather formulation (no float atomics):
//   h1 = x @ W1                         (bf16, [N,64])
//   CSR-sort edges by dst (per call)
//   gather1+layer2 fused: t = relu(segsum(h1[src]*w) + b1); h2 = t @ W2 (bf16, [N,32])
//   gather2: out = segsum(h2[src]*w) + b2   (f32)

typedef unsigned short u16;

static __device__ __forceinline__ float bf2f(u16 v) {
    return __uint_as_float(((unsigned int)v) << 16);
}
static __device__ __forceinline__ u16 f2bf(float f) {
    unsigned int u = __float_as_uint(f);
    return (u16)((u + 0x7fff + ((u >> 16) & 1)) >> 16);   // RNE
}

#define F4C(v, j) ((j)==0?(v).x:((j)==1?(v).y:((j)==2?(v).z:(v).w)))

// ---------------- GEMM1: h1 = x @ W1  (bf16 out) ----------------
__global__ __launch_bounds__(256, 2) void gemm1_kernel(
    const float* __restrict__ x, const float* __restrict__ W1,
    u16* __restrict__ h1, int N)
{
    __shared__ __align__(16) float xs[64][132];
    __shared__ __align__(16) float ws[128][64];
    const int tid  = threadIdx.x;
    const int row0 = blockIdx.x * 64;

    {   // stage W1 (2048 float4)
        const float4* W4 = (const float4*)W1;
        float4* d4 = (float4*)&ws[0][0];
        #pragma unroll
        for (int i = 0; i < 8; i++) d4[tid + i*256] = W4[tid + i*256];
    }
    {   // stage x tile (2048 float4)
        const float4* x4 = (const float4*)x;
        #pragma unroll
        for (int i = 0; i < 8; i++) {
            int idx = tid + i*256;
            int r = idx >> 5, kc = idx & 31;
            int gr = row0 + r;
            float4 v = make_float4(0.f,0.f,0.f,0.f);
            if (gr < N) v = x4[gr*32 + kc];
            *(float4*)&xs[r][kc*4] = v;
        }
    }
    __syncthreads();

    const int c0 = (tid & 15) * 4;
    const int r0 = (tid >> 4) * 4;
    float acc[4][4] = {};
    for (int k = 0; k < 128; k += 4) {
        float4 xv[4], wv[4];
        #pragma unroll
        for (int i = 0; i < 4; i++) xv[i] = *(const float4*)&xs[r0 + i][k];
        #pragma unroll
        for (int kk = 0; kk < 4; kk++) wv[kk] = *(const float4*)&ws[k + kk][c0];
        #pragma unroll
        for (int i = 0; i < 4; i++) {
            #pragma unroll
            for (int j = 0; j < 4; j++) {
                acc[i][j] += F4C(xv[i],0) * F4C(wv[0],j)
                           + F4C(xv[i],1) * F4C(wv[1],j)
                           + F4C(xv[i],2) * F4C(wv[2],j)
                           + F4C(xv[i],3) * F4C(wv[3],j);
            }
        }
    }
    #pragma unroll
    for (int i = 0; i < 4; i++) {
        int gr = row0 + r0 + i;
        if (gr < N) {
            ushort4 o;
            o.x = f2bf(acc[i][0]); o.y = f2bf(acc[i][1]);
            o.z = f2bf(acc[i][2]); o.w = f2bf(acc[i][3]);
            *(ushort4*)&h1[gr*64 + c0] = o;
        }
    }
}

// ---------------- CSR build ----------------
__global__ __launch_bounds__(256) void hist_kernel(
    const int* __restrict__ dst, int* __restrict__ counts, int E)
{
    int e = blockIdx.x * 256 + threadIdx.x;
    if (e < E) atomicAdd(&counts[dst[e]], 1);
}

__global__ __launch_bounds__(256) void scan_partial_kernel(
    const int* __restrict__ counts, int* __restrict__ partials, int N)
{
    __shared__ int s[256];
    int t = threadIdx.x;
    int i = blockIdx.x * 256 + t;
    s[t] = (i < N) ? counts[i] : 0;
    __syncthreads();
    for (int off = 128; off > 0; off >>= 1) {
        if (t < off) s[t] += s[t + off];
        __syncthreads();
    }
    if (t == 0) partials[blockIdx.x] = s[0];
}

__global__ __launch_bounds__(1024) void scan_top_kernel(
    const int* __restrict__ partials, int* __restrict__ partials_off, int B)
{
    __shared__ int s[1024];
    int t = threadIdx.x;
    int v = (t < B) ? partials[t] : 0;
    s[t] = v;
    __syncthreads();
    for (int off = 1; off < 1024; off <<= 1) {
        int add = (t >= off) ? s[t - off] : 0;
        __syncthreads();
        s[t] += add;
        __syncthreads();
    }
    if (t < B) partials_off[t] = s[t] - v;   // exclusive
}

__global__ __launch_bounds__(256) void scan_final_kernel(
    const int* __restrict__ counts, const int* __restrict__ partials_off,
    int* __restrict__ off, int N)
{
    __shared__ int s[256];
    int t = threadIdx.x;
    int i = blockIdx.x * 256 + t;
    int v = (i < N) ? counts[i] : 0;
    s[t] = v;
    __syncthreads();
    for (int o = 1; o < 256; o <<= 1) {
        int add = (t >= o) ? s[t - o] : 0;
        __syncthreads();
        s[t] += add;
        __syncthreads();
    }
    int excl = s[t] - v;
    int base = partials_off[blockIdx.x];
    if (i < N)     off[i] = base + excl;
    if (i == N-1)  off[N] = base + excl + v;   // == E
}

__global__ __launch_bounds__(256) void fill_kernel(
    const int* __restrict__ src, const int* __restrict__ dst,
    const float* __restrict__ w, const int* __restrict__ off,
    int* __restrict__ cursor, int2* __restrict__ es, int E)
{
    int e = blockIdx.x * 256 + threadIdx.x;
    if (e >= E) return;
    int d = dst[e];
    int pos = off[d] + atomicAdd(&cursor[d], 1);
    es[pos] = make_int2(src[e], __float_as_int(w[e]));
}

// ------- gather1 + layer2 fused: per dst node (1 wave), lane = feat -------
// t[64] = relu(sum_e h1[src]*w + b1); h2[32] = t @ W2  (bf16 out)
__global__ __launch_bounds__(256) void gather1_kernel(
    const u16* __restrict__ h1, const int2* __restrict__ es,
    const int* __restrict__ off, const float* __restrict__ b1,
    const float* __restrict__ W2, u16* __restrict__ h2, int N)
{
    __shared__ __align__(16) float w2s[64][32];
    __shared__ __align__(16) float b1s[64];
    __shared__ float ts[4][64];
    const int tid = threadIdx.x;

    {   // stage W2 (512 float4) + b1
        const float4* s4 = (const float4*)W2;
        float4* d4 = (float4*)&w2s[0][0];
        d4[tid] = s4[tid];
        d4[tid + 256] = s4[tid + 256];
        if (tid < 16) ((float4*)b1s)[tid] = ((const float4*)b1)[tid];
    }
    __syncthreads();

    const int wave = tid >> 6, lane = tid & 63;
    const int d = blockIdx.x * 4 + wave;
    if (d >= N) return;   // wave-uniform exit, after the only __syncthreads

    int pbeg = __builtin_amdgcn_readfirstlane(off[d]);
    int pend = __builtin_amdgcn_readfirstlane(off[d + 1]);

    float acc = 0.f;
    int p = pbeg;
    for (; p + 1 < pend; p += 2) {
        int2 e0 = es[p], e1 = es[p + 1];
        float v0 = bf2f(h1[(size_t)e0.x * 64 + lane]);
        float v1 = bf2f(h1[(size_t)e1.x * 64 + lane]);
        acc += v0 * __int_as_float(e0.y) + v1 * __int_as_float(e1.y);
    }
    if (p < pend) {
        int2 e0 = es[p];
        acc += bf2f(h1[(size_t)e0.x * 64 + lane]) * __int_as_float(e0.y);
    }
    float t = fmaxf(acc + b1s[lane], 0.f);
    ts[wave][lane] = t;
    // intra-wave LDS write->read: in-order wave issue + compiler lgkmcnt

    const int c = lane & 31, half = lane >> 5;
    float part = 0.f;
    #pragma unroll
    for (int j = 0; j < 32; j++) {
        part += ts[wave][half * 32 + j] * w2s[half * 32 + j][c];
    }
    part += __shfl_xor(part, 32, 64);
    if (half == 0) h2[(size_t)d * 32 + c] = f2bf(part);
}

// ------- gather2: out = segsum(h2[src]*w) + b2, 2 edges/wave, lane&31 = feat
__global__ __launch_bounds__(256) void gather2_kernel(
    const u16* __restrict__ h2, const int2* __restrict__ es,
    const int* __restrict__ off, const float* __restrict__ b2,
    float* __restrict__ out, int N)
{
    const int tid = threadIdx.x;
    const int wave = tid >> 6, lane = tid & 63;
    const int d = blockIdx.x * 4 + wave;
    if (d >= N) return;
    const int c = lane & 31, half = lane >> 5;

    int pbeg = __builtin_amdgcn_readfirstlane(off[d]);
    int pend = __builtin_amdgcn_readfirstlane(off[d + 1]);

    float acc = (half == 0) ? b2[c] : 0.f;
    for (int p = pbeg + half; p < pend; p += 2) {
        int2 e = es[p];
        acc += bf2f(h2[(size_t)e.x * 32 + c]) * __int_as_float(e.y);
    }
    acc += __shfl_xor(acc, 32, 64);
    if (half == 0) out[(size_t)d * 32 + c] = acc;
}

extern "C" void kernel_launch(void* const* d_in, const int* in_sizes, int n_in,
                              void* d_out, int out_size, void* d_ws, size_t ws_size,
                              hipStream_t stream)
{
    const float* x   = (const float*)d_in[0];
    const int*  esrc = (const int*)d_in[1];
    const int*  edst = (const int*)d_in[2];
    const float* ew  = (const float*)d_in[3];
    const float* W1  = (const float*)d_in[4];
    const float* b1  = (const float*)d_in[5];
    const float* W2  = (const float*)d_in[6];
    const float* b2  = (const float*)d_in[7];
    float* out = (float*)d_out;

    const int N = in_sizes[0] / 128;   // 100000
    const int E = in_sizes[1];         // 1600000

    // workspace layout (all 256B-aligned), total ~33 MB
    char* base = (char*)d_ws;
    size_t o = 0;
    auto alloc = [&](size_t bytes) { char* p = base + o; o = (o + bytes + 255) & ~(size_t)255; return p; };
    u16*  h1           = (u16*) alloc((size_t)N * 64 * 2);
    u16*  h2           = (u16*) alloc((size_t)N * 32 * 2);
    int2* es           = (int2*)alloc((size_t)E * 8);
    int*  off          = (int*) alloc((size_t)(N + 1) * 4);
    int*  cursor       = (int*) alloc((size_t)N * 4);
    int*  partials     = (int*) alloc(1024 * 4);
    int*  partials_off = (int*) alloc(1024 * 4);

    const int B = (N + 255) / 256;   // scan blocks (391)

    hipMemsetAsync(cursor, 0, (size_t)N * 4, stream);
    gemm1_kernel<<<(N + 63) / 64, 256, 0, stream>>>(x, W1, h1, N);
    hist_kernel<<<(E + 255) / 256, 256, 0, stream>>>(edst, cursor, E);
    scan_partial_kernel<<<B, 256, 0, stream>>>(cursor, partials, N);
    scan_top_kernel<<<1, 1024, 0, stream>>>(partials, partials_off, B);
    scan_final_kernel<<<B, 256, 0, stream>>>(cursor, partials_off, off, N);
    hipMemsetAsync(cursor, 0, (size_t)N * 4, stream);
    fill_kernel<<<(E + 255) / 256, 256, 0, stream>>>(esrc, edst, ew, off, cursor, es, E);
    gather1_kernel<<<(N + 3) / 4, 256, 0, stream>>>(h1, es, off, b1, W2, h2, N);
    gather2_kernel<<<(N + 3) / 4, 256, 0, stream>>>(h2, es, off, b2, out, N);
}

// Round 3
// 397.921 us; speedup vs baseline: 4.0937x; 3.6652x over previous
//
#include <hip/hip_runtime.h>
#include <hip/hip_bf16.h>

// GCN 2-layer, CSR-gather formulation (no float atomics):
//   h1 = bf16( bf16(x) @ bf16(W1) )     (MFMA 16x16x32, [N,64])
//   CSR-sort edges by dst (per call)
//   gather1+layer2 fused: t = relu(segsum(h1[src]*w) + b1); h2 = t @ W2 (bf16, [N,32])
//   gather2: out = segsum(h2[src]*w) + b2   (f32)

typedef unsigned short u16;
typedef short short8 __attribute__((ext_vector_type(8)));
typedef float floatx4 __attribute__((ext_vector_type(4)));

static __device__ __forceinline__ float bf2f(u16 v) {
    return __uint_as_float(((unsigned int)v) << 16);
}
static __device__ __forceinline__ u16 f2bf(float f) {
    unsigned int u = __float_as_uint(f);
    return (u16)((u + 0x7fff + ((u >> 16) & 1)) >> 16);   // RNE
}

#define F4C(v, j) ((j)==0?(v).x:((j)==1?(v).y:((j)==2?(v).z:(v).w)))

// ---------------- g1_mfma: h1 = x @ W1 via bf16 MFMA ----------------
// 64-row tile per block, 4 waves -> 16 rows each. K=128 in 4 MFMA steps.
// A-frag: A[m=lane&15][k=quad*8+j] ; B-frag: B[k=quad*8+j][n=lane&15]
// C/D:    col=lane&15, row=quad*4+reg   (verified layouts, learn_hip m89/m91)
__global__ __launch_bounds__(256, 4) void g1_mfma(
    const float* __restrict__ x, const float* __restrict__ W1,
    u16* __restrict__ h1, int N)
{
    __shared__ __align__(16) u16 xs[64][136];          // 64 rows x 128 k (pad 8)
    __shared__ __align__(16) u16 wf[4][4][64][8];      // [ntile][step][lane][j]
    const int tid  = threadIdx.x;
    const int row0 = blockIdx.x * 64;

    {   // stage W1 (128x64 f32) -> bf16, swizzled to B-fragment order
        const float4* W4 = (const float4*)W1;
        #pragma unroll
        for (int i = 0; i < 8; i++) {
            int idx = tid + i*256;                 // 2048 float4 = 8192 elems
            int k = idx >> 4, n4 = (idx & 15) * 4;
            float4 v = W4[idx];
            int step = k >> 5, klane = (k >> 3) & 3, j = k & 7;
            #pragma unroll
            for (int c = 0; c < 4; c++) {
                int n = n4 + c;
                wf[n >> 4][step][klane*16 + (n & 15)][j] = f2bf(F4C(v, c));
            }
        }
    }
    {   // stage x tile -> bf16
        const float4* x4 = (const float4*)x;
        #pragma unroll
        for (int i = 0; i < 8; i++) {
            int idx = tid + i*256;
            int r = idx >> 5, kc = idx & 31;
            int gr = row0 + r;
            float4 v = make_float4(0.f,0.f,0.f,0.f);
            if (gr < N) v = x4[gr*32 + kc];
            ushort4 o;
            o.x = f2bf(v.x); o.y = f2bf(v.y); o.z = f2bf(v.z); o.w = f2bf(v.w);
            *(ushort4*)&xs[r][kc*4] = o;
        }
    }
    __syncthreads();

    const int wave = tid >> 6, lane = tid & 63;
    const int m = lane & 15, quad = lane >> 4;
    const int rw = wave * 16;

    floatx4 acc[4] = {(floatx4)(0.f), (floatx4)(0.f), (floatx4)(0.f), (floatx4)(0.f)};
    #pragma unroll
    for (int step = 0; step < 4; step++) {
        short8 a = *(const short8*)&xs[rw + m][step*32 + quad*8];
        #pragma unroll
        for (int nt = 0; nt < 4; nt++) {
            short8 b = *(const short8*)&wf[nt][step][lane][0];
            acc[nt] = __builtin_amdgcn_mfma_f32_16x16x32_bf16(a, b, acc[nt], 0, 0, 0);
        }
    }
    #pragma unroll
    for (int nt = 0; nt < 4; nt++) {
        #pragma unroll
        for (int r = 0; r < 4; r++) {
            int gr = row0 + rw + quad*4 + r;
            if (gr < N) h1[(size_t)gr*64 + nt*16 + m] = f2bf(acc[nt][r]);
        }
    }
}

// ---------------- CSR build ----------------
__global__ __launch_bounds__(256) void hist_kernel(
    const int* __restrict__ dst, int* __restrict__ counts, int E)
{
    int e = blockIdx.x * 256 + threadIdx.x;
    if (e < E) atomicAdd(&counts[dst[e]], 1);
}

__global__ __launch_bounds__(256) void scan_partial_kernel(
    const int* __restrict__ counts, int* __restrict__ partials, int N)
{
    __shared__ int s[256];
    int t = threadIdx.x;
    int i = blockIdx.x * 256 + t;
    s[t] = (i < N) ? counts[i] : 0;
    __syncthreads();
    for (int off = 128; off > 0; off >>= 1) {
        if (t < off) s[t] += s[t + off];
        __syncthreads();
    }
    if (t == 0) partials[blockIdx.x] = s[0];
}

__global__ __launch_bounds__(1024) void scan_top_kernel(
    const int* __restrict__ partials, int* __restrict__ partials_off, int B)
{
    __shared__ int s[1024];
    int t = threadIdx.x;
    int v = (t < B) ? partials[t] : 0;
    s[t] = v;
    __syncthreads();
    for (int off = 1; off < 1024; off <<= 1) {
        int add = (t >= off) ? s[t - off] : 0;
        __syncthreads();
        s[t] += add;
        __syncthreads();
    }
    if (t < B) partials_off[t] = s[t] - v;   // exclusive
}

__global__ __launch_bounds__(256) void scan_final_kernel(
    const int* __restrict__ counts, const int* __restrict__ partials_off,
    int* __restrict__ off, int N)
{
    __shared__ int s[256];
    int t = threadIdx.x;
    int i = blockIdx.x * 256 + t;
    int v = (i < N) ? counts[i] : 0;
    s[t] = v;
    __syncthreads();
    for (int o = 1; o < 256; o <<= 1) {
        int add = (t >= o) ? s[t - o] : 0;
        __syncthreads();
        s[t] += add;
        __syncthreads();
    }
    int excl = s[t] - v;
    int base = partials_off[blockIdx.x];
    if (i < N)     off[i] = base + excl;
    if (i == N-1)  off[N] = base + excl + v;   // == E
}

// fill: place edge in its dst segment; order within segment irrelevant.
// Reuses counts[] via atomicSub -> no cursor memset needed.
__global__ __launch_bounds__(256) void fill_kernel(
    const int* __restrict__ src, const int* __restrict__ dst,
    const float* __restrict__ w, const int* __restrict__ off,
    int* __restrict__ counts, int2* __restrict__ es, int E)
{
    int e = blockIdx.x * 256 + threadIdx.x;
    if (e >= E) return;
    int d = dst[e];
    int r = atomicSub(&counts[d], 1) - 1;      // r in [0, cnt)
    es[off[d] + r] = make_int2(src[e], __float_as_int(w[e]));
}

// ------- gather1 + layer2 fused: per dst node (1 wave), lane = feat -------
__global__ __launch_bounds__(256) void gather1_kernel(
    const u16* __restrict__ h1, const int2* __restrict__ es,
    const int* __restrict__ off, const float* __restrict__ b1,
    const float* __restrict__ W2, u16* __restrict__ h2, int N)
{
    __shared__ __align__(16) float w2s[64][32];
    __shared__ __align__(16) float b1s[64];
    __shared__ float ts[4][64];
    const int tid = threadIdx.x;

    {   // stage W2 (512 float4) + b1
        const float4* s4 = (const float4*)W2;
        float4* d4 = (float4*)&w2s[0][0];
        d4[tid] = s4[tid];
        d4[tid + 256] = s4[tid + 256];
        if (tid < 16) ((float4*)b1s)[tid] = ((const float4*)b1)[tid];
    }
    __syncthreads();

    const int wave = tid >> 6, lane = tid & 63;
    const int d = blockIdx.x * 4 + wave;
    if (d >= N) return;   // wave-uniform exit, after the only __syncthreads

    int pbeg = __builtin_amdgcn_readfirstlane(off[d]);
    int pend = __builtin_amdgcn_readfirstlane(off[d + 1]);

    float acc = 0.f;
    int p = pbeg;
    for (; p + 3 < pend; p += 4) {
        int2 e0 = es[p], e1 = es[p+1], e2 = es[p+2], e3 = es[p+3];
        acc += bf2f(h1[(size_t)e0.x * 64 + lane]) * __int_as_float(e0.y)
             + bf2f(h1[(size_t)e1.x * 64 + lane]) * __int_as_float(e1.y)
             + bf2f(h1[(size_t)e2.x * 64 + lane]) * __int_as_float(e2.y)
             + bf2f(h1[(size_t)e3.x * 64 + lane]) * __int_as_float(e3.y);
    }
    for (; p < pend; p++) {
        int2 e0 = es[p];
        acc += bf2f(h1[(size_t)e0.x * 64 + lane]) * __int_as_float(e0.y);
    }
    float t = fmaxf(acc + b1s[lane], 0.f);
    ts[wave][lane] = t;
    // intra-wave LDS write->read: in-order wave issue + compiler lgkmcnt

    const int c = lane & 31, half = lane >> 5;
    float part = 0.f;
    #pragma unroll
    for (int j = 0; j < 32; j++) {
        part += ts[wave][half * 32 + j] * w2s[half * 32 + j][c];
    }
    part += __shfl_xor(part, 32, 64);
    if (half == 0) h2[(size_t)d * 32 + c] = f2bf(part);
}

// ------- gather2: out = segsum(h2[src]*w) + b2, 2 edges/wave, lane&31 = feat
__global__ __launch_bounds__(256) void gather2_kernel(
    const u16* __restrict__ h2, const int2* __restrict__ es,
    const int* __restrict__ off, const float* __restrict__ b2,
    float* __restrict__ out, int N)
{
    const int tid = threadIdx.x;
    const int wave = tid >> 6, lane = tid & 63;
    const int d = blockIdx.x * 4 + wave;
    if (d >= N) return;
    const int c = lane & 31, half = lane >> 5;

    int pbeg = __builtin_amdgcn_readfirstlane(off[d]);
    int pend = __builtin_amdgcn_readfirstlane(off[d + 1]);

    float acc = (half == 0) ? b2[c] : 0.f;
    int p = pbeg + half;
    for (; p + 2 < pend; p += 4) {
        int2 ea = es[p], eb = es[p + 2];
        acc += bf2f(h2[(size_t)ea.x * 32 + c]) * __int_as_float(ea.y)
             + bf2f(h2[(size_t)eb.x * 32 + c]) * __int_as_float(eb.y);
    }
    if (p < pend) {
        int2 ea = es[p];
        acc += bf2f(h2[(size_t)ea.x * 32 + c]) * __int_as_float(ea.y);
    }
    acc += __shfl_xor(acc, 32, 64);
    if (half == 0) out[(size_t)d * 32 + c] = acc;
}

extern "C" void kernel_launch(void* const* d_in, const int* in_sizes, int n_in,
                              void* d_out, int out_size, void* d_ws, size_t ws_size,
                              hipStream_t stream)
{
    const float* x   = (const float*)d_in[0];
    const int*  esrc = (const int*)d_in[1];
    const int*  edst = (const int*)d_in[2];
    const float* ew  = (const float*)d_in[3];
    const float* W1  = (const float*)d_in[4];
    const float* b1  = (const float*)d_in[5];
    const float* W2  = (const float*)d_in[6];
    const float* b2  = (const float*)d_in[7];
    float* out = (float*)d_out;

    const int N = in_sizes[0] / 128;   // 100000
    const int E = in_sizes[1];         // 1600000

    char* base = (char*)d_ws;
    size_t o = 0;
    auto alloc = [&](size_t bytes) { char* p = base + o; o = (o + bytes + 255) & ~(size_t)255; return p; };
    u16*  h1           = (u16*) alloc((size_t)N * 64 * 2);
    u16*  h2           = (u16*) alloc((size_t)N * 32 * 2);
    int2* es           = (int2*)alloc((size_t)E * 8);
    int*  off          = (int*) alloc((size_t)(N + 1) * 4);
    int*  counts       = (int*) alloc((size_t)N * 4);
    int*  partials     = (int*) alloc(1024 * 4);
    int*  partials_off = (int*) alloc(1024 * 4);

    const int B = (N + 255) / 256;   // 391 scan blocks

    hipMemsetAsync(counts, 0, (size_t)N * 4, stream);
    g1_mfma<<<(N + 63) / 64, 256, 0, stream>>>(x, W1, h1, N);
    hist_kernel<<<(E + 255) / 256, 256, 0, stream>>>(edst, counts, E);
    scan_partial_kernel<<<B, 256, 0, stream>>>(counts, partials, N);
    scan_top_kernel<<<1, 1024, 0, stream>>>(partials, partials_off, B);
    scan_final_kernel<<<B, 256, 0, stream>>>(counts, partials_off, off, N);
    fill_kernel<<<(E + 255) / 256, 256, 0, stream>>>(esrc, edst, ew, off, counts, es, E);
    gather1_kernel<<<(N + 3) / 4, 256, 0, stream>>>(h1, es, off, b1, W2, h2, N);
    gather2_kernel<<<(N + 3) / 4, 256, 0, stream>>>(h2, es, off, b2, out, N);
}